// Round 12
// baseline (12786.083 us; speedup 1.0000x reference)
//
#include <hip/hip_runtime.h>
#include <math.h>

#define S_LEN 4096
#define HID   2048
#define NBLK  256
#define NTHR  512   // 8 waves/block, 1 block/CU

typedef unsigned int       u32;
typedef unsigned long long u64;
typedef unsigned u32x4 __attribute__((ext_vector_type(4)));

// R16: dissolve both barriers into dataflow flags (R10's idea, minus its
//  implementation mistakes: no dedicated wave, no ballot gating, no volley
//  quantization, no permanent setprio).
//  Key structural fact: wave w's poll range (threads 64w..64w+63 polling
//  units 4*tid..4*tid+3) IS FMA-chunk w, and lane l of wave w stages exactly
//  the float4 (hl[l+64w]) that lane l itself reads for slice w. So:
//  - barrier A -> ck[p][w] epoch flags: wave w polls+stages chunk w, flags;
//    FMA loop spins on ck[p][j] only at slice j (own slice: no flag needed,
//    data is the lane's own in-order DS write). A late chunk delays only its
//    own 64cy slice, not the whole phase.
//  - barrier B -> gep[p][w] epoch flags: only wave 0 (tail owner, cx holder)
//    waits; waves 1-7 launch into step t+1's poll while wave 0 runs the
//    tail -> 7/8 of next-step detect overlaps our tail+publish (detect
//    becomes ~flight-only instead of phase+flight).
//  - counter gate dropped: it serialized an extra counter-RTT before the
//    volley; with per-wave spinning pollers it is redundant.
//  Safety (monotonic epoch flags, parity double-buffer):
//  - WAR on hx_lds[p][chunk w] at step t vs reads at t-2: staging t requires
//    polling all t tags -> our block published t (end of t-1) -> wave 0
//    passed gep-spin(t-1) -> all waves stored gates t-1 -> all finished FMA
//    t-1, a fortiori FMA t-2. Same chain covers gates_lds[p] reuse.
//  - ck/gep values are step+1 (monotone); spin is >=, so overwrite by a
//    later epoch can never deadlock a lagging reader.
//  Falsification ledger feeding this design: weight residency dead (dur
//  insensitive to FETCH 468-844MB across R8/R9/R14/R15); sync request rate
//  (R4/R9), population (R12), pacing (R11) all +-2%; R13's per-wave 4B
//  publishes (WRITE 295MB partial-line RMW) mandate the coalesced 32B
//  publish kept here. Remaining cost = serial phase chain; this round
//  overlaps the phases.
//  Tag scheme unchanged (validated R6-R15): value with 2-LSB tag, want
//  ((t+1)&3)^2, exclusive 64B line per block (words 0..7 parity0, 8..15
//  parity1), 0xAA poison unreachable by same-address monotonicity.

__device__ __forceinline__ float fast_sigmoid(float x) {
    float e = __builtin_amdgcn_exp2f(-1.44269504f * x);   // 2^(-x*log2e)
    return __builtin_amdgcn_rcpf(1.0f + e);
}

__global__ __launch_bounds__(NTHR)
__attribute__((amdgpu_waves_per_eu(2, 2)))
void qlstm_persistent(const float* __restrict__ inp,     // (S,1,4)
                      const float* __restrict__ conv_w,  // (4)
                      const float* __restrict__ conv_b,  // (1)
                      const float* __restrict__ Wg,      // (2049, 8192) row-major
                      const float* __restrict__ bg,      // (8192)
                      float* __restrict__ out,           // S*H + H + H
                      float* __restrict__ ws)            // scratch (poison 0xAA ok)
{
    const int b   = blockIdx.x;
    const int tid = threadIdx.x;
    const int l   = tid & 63;
    const int wv  = tid >> 6;

    u32* tbl = (u32*)ws;   // [NBLK][16]: exclusive 64B line per block

    __shared__ __align__(16) float hx_lds[2][HID];
    __shared__ __align__(16) float conv_lds[S_LEN];
    __shared__ float gates_lds[2][32];
    __shared__ float colw0[32];
    __shared__ float colb[32];
    __shared__ u32 ck[2][8];    // per-parity per-chunk staged epoch (step+1)
    __shared__ u32 gep[2][8];   // per-parity per-wave gates epoch (step+1)

    // ---------------- init phase ----------------
    {
        const float cw0 = conv_w[0], cw1 = conv_w[1], cw2 = conv_w[2], cw3 = conv_w[3];
        const float cb  = conv_b[0];
        for (int g = tid; g < S_LEN; g += NTHR) {
            float4 x = ((const float4*)inp)[g];
            float v = x.x*cw0 + x.y*cw1 + x.z*cw2 + x.w*cw3 + cb;
            conv_lds[g] = fast_sigmoid(v);
        }
    }
    // hx_0 = 0 prestaged in parity 0: step 0 needs no global exchange.
    ((float4*)hx_lds[0])[tid] = make_float4(0.f, 0.f, 0.f, 0.f);
    if (tid < 8) {
        ck[0][tid]  = 1u;   // parity 0 staged for t=0
        ck[1][tid]  = 0u;
        gep[0][tid] = 0u;
        gep[1][tid] = 0u;
    }

    // this wave's 4 global column indices
    int jcol[4];
    #pragma unroll
    for (int c = 0; c < 4; ++c) {
        int cgi  = 4*wv + c;
        int gate = cgi >> 3;
        int mi   = cgi & 7;
        jcol[c]  = (gate << 11) + (b * 8 + mi);     // gate*2048 + m
    }
    if (l == 0) {
        #pragma unroll
        for (int c = 0; c < 4; ++c) {
            int cgi = 4*wv + c;
            colw0[cgi] = Wg[jcol[c]];               // row 0 = input (c_t) weight
            colb[cgi]  = bg[jcol[c]];
        }
    }

    // W registers: wreg[c][4j+r] = W[1 + 4l + 256j + r][jcol[c]]
    float wreg[4][32];
    #pragma unroll
    for (int j = 0; j < 8; ++j)
        #pragma unroll
        for (int r = 0; r < 4; ++r) {
            const float* rowp = Wg + (size_t)(1 + 4*l + 256*j + r) * 8192;
            #pragma unroll
            for (int c = 0; c < 4; ++c)
                wreg[c][4*j + r] = rowp[jcol[c]];
        }

    float cx = 0.0f;                    // live only in wave-0 lanes<8
    const int m_out = b * 8 + tid;      // hidden index for tid<8

    // thread tid polls units 4*tid..4*tid+3 (= chunk wv, its own FMA slice):
    // block tid>>1, words (tid&1)*4.. within the parity half-line.
    const u32* poll_base = tbl + (tid >> 1) * 16 + (tid & 1) * 4;
    u32* pub_base = tbl + b * 16 + tid;      // + parity*8 at publish (tid<8)

    __syncthreads();    // init complete (the only full barrier)

    // ---------------- recurrence ----------------
    for (int t = 0; t < S_LEN; ++t) {
        const int p   = t & 1;
        const u32 stp = (u32)(t + 1);       // epoch value for this step

        if (t) {
            // ---- poll own chunk (tag-verified volley), stage, flag ----
            const u32 want = (stp & 3u) ^ 2u;
            const u32* pp = poll_base + (p << 3);
            u32x4 q;
            u32 miss;
            do {
                asm volatile("global_load_dwordx4 %0, %1, off sc0 sc1\n\t"
                             "s_waitcnt vmcnt(0)"
                             : "=v"(q) : "v"(pp) : "memory");
                miss = ((q[0] ^ want) & 3u) | ((q[1] ^ want) & 3u)
                     | ((q[2] ^ want) & 3u) | ((q[3] ^ want) & 3u);
            } while (miss);
            u32x4 st;
            st[0] = q[0] & ~3u; st[1] = q[1] & ~3u;
            st[2] = q[2] & ~3u; st[3] = q[3] & ~3u;
            ((u32x4*)hx_lds[p])[tid] = st;          // lane's own slice data
            if (l == 0)                              // release: after DS write
                __hip_atomic_store(&ck[p][wv], stp, __ATOMIC_RELEASE,
                                   __HIP_MEMORY_SCOPE_WORKGROUP);
        }

        // ---- FMA: spin per-chunk flag only at that slice (own: no flag) ----
        const float4* hl = (const float4*)hx_lds[p];
        float acc0 = 0.f, acc1 = 0.f, acc2 = 0.f, acc3 = 0.f;
        #pragma unroll
        for (int j = 0; j < 8; ++j) {
            if (t && j != wv) {
                while (__hip_atomic_load(&ck[p][j], __ATOMIC_ACQUIRE,
                                         __HIP_MEMORY_SCOPE_WORKGROUP) < stp) {}
            }
            float4 h = hl[l + 64*j];        // ds_read_b128, conflict-free
            acc0 = fmaf(h.x, wreg[0][4*j+0], acc0);
            acc1 = fmaf(h.x, wreg[1][4*j+0], acc1);
            acc2 = fmaf(h.x, wreg[2][4*j+0], acc2);
            acc3 = fmaf(h.x, wreg[3][4*j+0], acc3);
            acc0 = fmaf(h.y, wreg[0][4*j+1], acc0);
            acc1 = fmaf(h.y, wreg[1][4*j+1], acc1);
            acc2 = fmaf(h.y, wreg[2][4*j+1], acc2);
            acc3 = fmaf(h.y, wreg[3][4*j+1], acc3);
            acc0 = fmaf(h.z, wreg[0][4*j+2], acc0);
            acc1 = fmaf(h.z, wreg[1][4*j+2], acc1);
            acc2 = fmaf(h.z, wreg[2][4*j+2], acc2);
            acc3 = fmaf(h.z, wreg[3][4*j+2], acc3);
            acc0 = fmaf(h.w, wreg[0][4*j+3], acc0);
            acc1 = fmaf(h.w, wreg[1][4*j+3], acc1);
            acc2 = fmaf(h.w, wreg[2][4*j+3], acc2);
            acc3 = fmaf(h.w, wreg[3][4*j+3], acc3);
        }
        #pragma unroll
        for (int off = 32; off; off >>= 1) {
            acc0 += __shfl_down(acc0, off, 64);
            acc1 += __shfl_down(acc1, off, 64);
            acc2 += __shfl_down(acc2, off, 64);
            acc3 += __shfl_down(acc3, off, 64);
        }
        if (l == 0) {
            gates_lds[p][4*wv + 0] = acc0;
            gates_lds[p][4*wv + 1] = acc1;
            gates_lds[p][4*wv + 2] = acc2;
            gates_lds[p][4*wv + 3] = acc3;
            __hip_atomic_store(&gep[p][wv], stp, __ATOMIC_RELEASE,
                               __HIP_MEMORY_SCOPE_WORKGROUP);
        }

        // ---- tail: wave 0 only; waves 1-7 fall through to next poll ----
        if (wv == 0) {
            u32 g;
            do {
                g = __hip_atomic_load(&gep[p][l & 7], __ATOMIC_ACQUIRE,
                                      __HIP_MEMORY_SCOPE_WORKGROUP);
            } while (!__all(g >= stp));
            __builtin_amdgcn_s_setprio(1);
            if (l < 8) {
                float ct = conv_lds[t];
                float fg = gates_lds[p][tid]      + ct*colw0[tid]      + colb[tid];
                float ig = gates_lds[p][8 + tid]  + ct*colw0[8 + tid]  + colb[8 + tid];
                float gg = gates_lds[p][16 + tid] + ct*colw0[16 + tid] + colb[16 + tid];
                float og = gates_lds[p][24 + tid] + ct*colw0[24 + tid] + colb[24 + tid];
                float f  = fast_sigmoid(fg);
                float ii = fast_sigmoid(ig);
                float gv = 2.0f * fast_sigmoid(2.0f * gg) - 1.0f;   // tanh
                float o  = fast_sigmoid(og);
                cx = f * cx + ii * gv;
                float hx = o * (2.0f * fast_sigmoid(2.0f * cx) - 1.0f);
                if (t < S_LEN - 1) {
                    // coalesced 32B publish into the block's OWN line
                    u32 word = (__float_as_uint(hx) & ~3u)
                             | (((u32)(t + 2) & 3u) ^ 2u);
                    __hip_atomic_store(pub_base + (((t + 1) & 1) << 3), word,
                                       __ATOMIC_RELAXED, __HIP_MEMORY_SCOPE_AGENT);
                }
                out[(size_t)t * HID + m_out] = hx;
                if (t == S_LEN - 1) {
                    out[(size_t)S_LEN * HID + m_out]       = hx;   // final hx
                    out[(size_t)S_LEN * HID + HID + m_out] = cx;   // final cx
                }
            }
            __builtin_amdgcn_s_setprio(0);
        }
    }
}

extern "C" void kernel_launch(void* const* d_in, const int* in_sizes, int n_in,
                              void* d_out, int out_size, void* d_ws, size_t ws_size,
                              hipStream_t stream) {
    const float* inp    = (const float*)d_in[0];
    const float* conv_w = (const float*)d_in[1];
    const float* conv_b = (const float*)d_in[2];
    const float* Wg     = (const float*)d_in[3];
    const float* bg     = (const float*)d_in[4];
    float* out = (float*)d_out;
    float* ws  = (float*)d_ws;

    // no memset needed: tag poison unreachable (R9 proof); all flags are LDS.
    void* args[] = {(void*)&inp, (void*)&conv_w, (void*)&conv_b,
                    (void*)&Wg, (void*)&bg, (void*)&out, (void*)&ws};
    hipLaunchCooperativeKernel((void*)qlstm_persistent,
                               dim3(NBLK), dim3(NTHR), args, 0, stream);
}